// Round 2
// baseline (638.249 us; speedup 1.0000x reference)
//
#include <hip/hip_runtime.h>

#define NNODES 102400
#define NBATCH 256
#define LSEQ   400
#define SPAD   416   // 8 zero pad rows each side of the 400 valid positions
#define HS     256
#define KDIM   640
#define OC     128
#define NTAP   15
#define H1     512
#define STILE  80    // 5 * 80 = 400 exact: no M-padding waste, no s-guards
#define SROWS  94    // STILE + 14 halo rows

typedef __attribute__((ext_vector_type(8))) short short8;
typedef __attribute__((ext_vector_type(4))) float floatx4;

__device__ inline unsigned short f2bf(float f) {
    unsigned u = __builtin_bit_cast(unsigned, f);
    unsigned r = (u + 0x7FFFu + ((u >> 16) & 1u)) >> 16;
    return (unsigned short)r;
}

__device__ inline void gld_lds16(const void* g, void* l) {
    __builtin_amdgcn_global_load_lds(
        (const __attribute__((address_space(1))) unsigned int*)g,
        (__attribute__((address_space(3))) unsigned int*)l, 16, 0, 0);
}

// ------- fused setup: seq pad-zero, A_acc zero, conv-kernel combine, packs -
__global__ __launch_bounds__(256) void setup_all(
    const float* __restrict__ k7, const float* __restrict__ k11,
    const float* __restrict__ k15, const float* __restrict__ cb7,
    const float* __restrict__ cb11, const float* __restrict__ cb15,
    const float* __restrict__ W_le, const float* __restrict__ Wl1,
    unsigned short* __restrict__ Wpk, float* __restrict__ bc,
    unsigned short* __restrict__ Wle_pk, unsigned short* __restrict__ Wl1_pk,
    unsigned short* __restrict__ seq, float* __restrict__ A_acc)
{
    int bid = blockIdx.x, tid = threadIdx.x;
    if (bid < 512) {
        // zero only the 16 pad rows per batch (replaces 54 MB memset)
        int idx = bid * 256 + tid;                 // 256 batches * 512 uint4
        int b = idx >> 9, within = idx & 511;
        int rowi = within >> 5, c = within & 31;
        int srow = rowi < 8 ? rowi : 400 + rowi;
        ((uint4*)seq)[((size_t)b * SPAD + srow) * 32 + c] = make_uint4(0u, 0u, 0u, 0u);
    } else if (bid < 2432) {
        // combine k7/k11/k15 (+/3) into one 15-tap weight, MFMA B-frag order
        int idx = (bid - 512) * 256 + tid;         // 15*256*128 = 1920 blocks exact
        int oc = idx & (OC - 1);
        int ic = (idx >> 7) & (HS - 1);
        int d  = idx / (OC * HS);
        float wv = k15[(oc * HS + ic) * 15 + d];
        int t11 = d - 2;
        if (t11 >= 0 && t11 < 11) wv += k11[(oc * HS + ic) * 11 + t11];
        int t7 = d - 4;
        if (t7 >= 0 && t7 < 7)   wv += k7[(oc * HS + ic) * 7 + t7];
        wv *= (1.0f / 3.0f);
        int kc = ic >> 6, ks = (ic >> 5) & 1, qq = (ic >> 3) & 3, j = ic & 7;
        int nt = oc >> 4, n = oc & 15;
        int pidx = ((((d * 4 + kc) * 2 + ks) * 8 + nt) * 64 + (qq * 16 + n)) * 8 + j;
        Wpk[pidx] = f2bf(wv);
        if (idx < OC) bc[idx] = (cb7[idx] + cb11[idx] + cb15[idx]) * (1.0f / 3.0f);
    } else if (bid < 3072) {
        // pack W_le [640][256] -> bf16 fragment order (10 stages of BK=64)
        int idx = (bid - 2432) * 256 + tid;        // 640*256 = 640 blocks
        int k = idx >> 8, col = idx & 255;
        int t = k >> 6, ks = (k >> 5) & 1, qq = (k >> 3) & 3, j = k & 7;
        int nt = col >> 4, n = col & 15;
        int pidx = (((t * 2 + ks) * 16 + nt) * 64 + (qq * 16 + n)) * 8 + j;
        Wle_pk[pidx] = f2bf(W_le[k * 256 + col]);
    } else if (bid < 3328) {
        // pack Wl1 [128][512] -> bf16 fragment order (4 j-blocks of 128)
        int idx = (bid - 3072) * 256 + tid;        // 128*512 = 256 blocks
        int k = idx >> 9, col = idx & 511;
        int ks = k >> 5, qq = (k >> 3) & 3, j = k & 7;
        int jbb = col >> 7, nhnt = (col >> 4) & 7, n = col & 15;
        int pidx = jbb * 16384 + ((ks * 8 + nhnt) * 64 + (qq * 16 + n)) * 8 + j;
        Wl1_pk[pidx] = f2bf(Wl1[k * 512 + col]);
    } else {
        // zero A_acc: 256*512 f32 = 32768 float4 = 128 blocks
        int idx = (bid - 3328) * 256 + tid;
        ((float4*)A_acc)[idx] = make_float4(0.f, 0.f, 0.f, 0.f);
    }
}

// ------- MFMA: relu(emb @ W_le + b_le), + (x_r + .)/2 scatter into bf16 seq
// 128x256 tile (was 64x256): 64 MFMA/wave/stage between barriers (was 32),
// B L2 traffic halved (800 blocks), epilogue in two 64-row Cs passes.
union GemmSm {
    struct { unsigned short As[128][72]; unsigned short Bsh[16384]; } s;  // 51200 B
    unsigned short Cs[64][264];                                           // 33792 B
};

__global__ __launch_bounds__(256) void gemm_emb(
    const float* __restrict__ emb, const int* __restrict__ x_tokens,
    const float* __restrict__ emb_table,
    const unsigned short* __restrict__ Wle_pk, const float* __restrict__ b_le,
    unsigned short* __restrict__ seq)
{
    __shared__ __align__(16) GemmSm g;
    int row0 = blockIdx.x * 128;
    int tid = threadIdx.x;
    int w = tid >> 6, lane = tid & 63;
    int q = lane >> 4, m = lane & 15;
    int mh = w >> 1, nh = w & 1;

    int ar = tid >> 1;            // 128 rows, 2 threads per row
    int ac = (tid & 1) * 32;      // each thread: 32 cols = 8 float4

    floatx4 acc[4][8] = {};
    const uint4* wp = (const uint4*)Wle_pk;

    for (int t = 0; t < 10; t++) {
        __syncthreads();
        {
            const float4* src = (const float4*)&emb[(size_t)(row0 + ar) * KDIM + t * 64 + ac];
            #pragma unroll
            for (int u = 0; u < 8; u++) {
                float4 f = src[u];
                ushort4 h;
                h.x = f2bf(f.x); h.y = f2bf(f.y); h.z = f2bf(f.z); h.w = f2bf(f.w);
                *(ushort4*)&g.s.As[ar][ac + u * 4] = h;
            }
        }
        #pragma unroll
        for (int i = 0; i < 8; i++) {
            gld_lds16(wp + (size_t)t * 2048 + i * 256 + tid,
                      &g.s.Bsh[(size_t)(i * 256 + w * 64) * 8]);
        }
        __syncthreads();

        #pragma unroll
        for (int ks = 0; ks < 2; ks++) {
            short8 a0 = *(const short8*)&g.s.As[mh * 64 +  0 + m][ks * 32 + q * 8];
            short8 a1 = *(const short8*)&g.s.As[mh * 64 + 16 + m][ks * 32 + q * 8];
            short8 a2 = *(const short8*)&g.s.As[mh * 64 + 32 + m][ks * 32 + q * 8];
            short8 a3 = *(const short8*)&g.s.As[mh * 64 + 48 + m][ks * 32 + q * 8];
            #pragma unroll
            for (int nt = 0; nt < 8; nt++) {
                short8 bf = *(const short8*)&g.s.Bsh[(size_t)((ks * 16 + nh * 8 + nt) * 64 + lane) * 8];
                acc[0][nt] = __builtin_amdgcn_mfma_f32_16x16x32_bf16(a0, bf, acc[0][nt], 0, 0, 0);
                acc[1][nt] = __builtin_amdgcn_mfma_f32_16x16x32_bf16(a1, bf, acc[1][nt], 0, 0, 0);
                acc[2][nt] = __builtin_amdgcn_mfma_f32_16x16x32_bf16(a2, bf, acc[2][nt], 0, 0, 0);
                acc[3][nt] = __builtin_amdgcn_mfma_f32_16x16x32_bf16(a3, bf, acc[3][nt], 0, 0, 0);
            }
        }
    }

    // epilogue in two 64-row halves through the Cs tile
    #pragma unroll
    for (int h = 0; h < 2; h++) {
        __syncthreads();               // h=0: As/Bsh reads done; h=1: half-0 stores done
        if (mh == h) {
            #pragma unroll
            for (int mt = 0; mt < 4; mt++) {
                #pragma unroll
                for (int r = 0; r < 4; r++) {
                    int lrow = mt * 16 + q * 4 + r;          // 0..63 within half
                    int tokb = x_tokens[row0 + h * 64 + lrow] * HS;
                    #pragma unroll
                    for (int nt = 0; nt < 8; nt++) {
                        int col = nh * 128 + nt * 16 + m;
                        float v = acc[mt][nt][r] + b_le[col];
                        v = v > 0.f ? v : 0.f;
                        g.Cs[lrow][col] = f2bf(0.5f * (v + emb_table[tokb + col]));
                    }
                }
            }
        }
        __syncthreads();
        // coalesced row stores: wave w owns rows w*16..w*16+15 of this half
        #pragma unroll
        for (int rr = 0; rr < 16; rr++) {
            int node = row0 + h * 64 + w * 16 + rr;
            int b = node / LSEQ;
            int p = node - b * LSEQ;
            ushort4 val = *(const ushort4*)&g.Cs[w * 16 + rr][lane * 4];
            *(ushort4*)&seq[((size_t)b * SPAD + (p + 8)) * HS + lane * 4] = val;
        }
    }
}

// ------- conv + mlp1 fused, v2: 3 blocks/CU (LDS 49632, VGPR<=170),
// half-chunk B pipeline (32 buffer VGPRs), kh-reduction in two 40-row
// halves, MLP B read direct global->regs (no Bsh, no MLP barriers).
union ConvSm {
    unsigned short As[SROWS][264];                 // 49632 B (conv phase)
    struct {
        float red[40 * 132];                       // 21120 B (half reduction)
        unsigned short abf[STILE][136];            // 21760 B (mlp A-tile)
    } p2;                                          // 42880 B
};

__device__ __forceinline__ void conv_load_Bh(
    const short8* __restrict__ wb, int h, int kh, int nh, int lane, short8 bf[4])
{
    int c = h >> 1, ks = h & 1;
    int d = c >> 1, kc = kh * 2 + (c & 1);
    const short8* bp = wb + (size_t)(d * 4 + kc) * 1024 + nh * 256 + ks * 512 + lane;
    #pragma unroll
    for (int nt = 0; nt < 4; nt++)
        bf[nt] = bp[nt * 64];
}

__device__ __forceinline__ void conv_mfma_half(
    const unsigned short (*As)[264], floatx4 acc[5][4],
    const short8 bf[4], int h, int kh, int m, int q)
{
    int c = h >> 1, ks = h & 1;
    int d = c >> 1, kc = kh * 2 + (c & 1);
    #pragma unroll
    for (int mt = 0; mt < 5; mt++) {
        short8 a = *(const short8*)&As[mt * 16 + m + d][kc * 64 + ks * 32 + q * 8];
        #pragma unroll
        for (int nt = 0; nt < 4; nt++)
            acc[mt][nt] = __builtin_amdgcn_mfma_f32_16x16x32_bf16(a, bf[nt], acc[mt][nt], 0, 0, 0);
    }
}

__global__ __launch_bounds__(256, 3) void conv_fused(
    const unsigned short* __restrict__ seq, const unsigned short* __restrict__ Wpk,
    const float* __restrict__ bc, const unsigned short* __restrict__ Wl1_pk,
    const float* __restrict__ bl1, float* __restrict__ A_acc)
{
    __shared__ __align__(16) ConvSm sm;

    int b  = blockIdx.y;
    int s0 = blockIdx.x * STILE;                 // 0,80,160,240,320
    int tid = threadIdx.x;
    int w = tid >> 6, lane = tid & 63;
    int q = lane >> 4, m = lane & 15;
    int nh = w >> 1, kh = w & 1;

    const short8* wb = (const short8*)Wpk;
    short8 bA[4], bB[4];
    conv_load_Bh(wb, 0, kh, nh, lane, bA);       // overlap with A staging

    // stage A once: seq rows s0+1 .. s0+94, all 256 ic (bf16).
    // Max row = 320+1+93 = 414 < SPAD=416 -> always in-bounds.
    {
        const uint4* sp = (const uint4*)(seq + ((size_t)b * SPAD + s0 + 1) * HS);
        #pragma unroll
        for (int pass = 0; pass < 12; pass++) {
            int idx = pass * 256 + tid;
            if (idx < SROWS * 32) {
                int r = idx >> 5, c = idx & 31;
                *(uint4*)&sm.As[r][c * 8] = sp[r * 32 + c];
            }
        }
    }
    __syncthreads();

    floatx4 acc[5][4] = {};   // 80 s x 64 oc partial (this wave's ic-half)

    // 60 half-chunks = 15 taps x 2 kc x 2 ks, pipelined by one half-chunk
    for (int h = 0; h < 60; h += 2) {
        conv_load_Bh(wb, h + 1, kh, nh, lane, bB);
        conv_mfma_half(sm.As, acc, bA, h, kh, m, q);
        if (h + 2 < 60) conv_load_Bh(wb, h + 2, kh, nh, lane, bA);
        conv_mfma_half(sm.As, acc, bB, h + 1, kh, m, q);
    }

    // ---- kh-pair reduce + bias + bf16 in two 40-row halves ----------------
    float bc0 = bc[lane * 2], bc1 = bc[lane * 2 + 1];
    __syncthreads();                       // all As reads done; alias as p2
    #pragma unroll
    for (int hh = 0; hh < 2; hh++) {
        if (kh == 1) {
            #pragma unroll
            for (int mt = 0; mt < 5; mt++)
                #pragma unroll
                for (int nt = 0; nt < 4; nt++)
                    #pragma unroll
                    for (int r = 0; r < 4; r++) {
                        int row = mt * 16 + q * 4 + r;
                        if (row >= hh * 40 && row < hh * 40 + 40)
                            sm.p2.red[(row - hh * 40) * 132 + nh * 64 + nt * 16 + m] = acc[mt][nt][r];
                    }
        }
        __syncthreads();
        if (kh == 0) {
            #pragma unroll
            for (int mt = 0; mt < 5; mt++)
                #pragma unroll
                for (int nt = 0; nt < 4; nt++)
                    #pragma unroll
                    for (int r = 0; r < 4; r++) {
                        int row = mt * 16 + q * 4 + r;
                        if (row >= hh * 40 && row < hh * 40 + 40)
                            sm.p2.red[(row - hh * 40) * 132 + nh * 64 + nt * 16 + m] += acc[mt][nt][r];
                    }
        }
        __syncthreads();
        // convert 40 rows: each wave 10 rows
        #pragma unroll
        for (int rr = 0; rr < 10; rr++) {
            int lrow = w * 10 + rr;
            float2 v = *(const float2*)&sm.p2.red[lrow * 132 + lane * 2];
            unsigned uo = (unsigned)f2bf(v.x + bc0) | ((unsigned)f2bf(v.y + bc1) << 16);
            *(unsigned*)&sm.p2.abf[hh * 40 + lrow][lane * 2] = uo;
        }
        __syncthreads();                   // red free for next half / abf ready
    }

    // ---- fused MLP1: colsum_s relu(abf @ Wl1 + bl1) -> atomicAdd A_acc ----
    // B frags direct global->reg (each wave uses disjoint cols: LDS staging
    // would save zero L2 traffic). 2-deep jb pipeline, no barriers.
    const short8* wl1 = (const short8*)Wl1_pk;
    short8 f0[8], f1[8];
    #pragma unroll
    for (int ks = 0; ks < 4; ks++)
        #pragma unroll
        for (int nt = 0; nt < 2; nt++)
            f0[ks * 2 + nt] = wl1[(ks * 8 + w * 2 + nt) * 64 + lane];
    #pragma unroll
    for (int ks = 0; ks < 4; ks++)
        #pragma unroll
        for (int nt = 0; nt < 2; nt++)
            f1[ks * 2 + nt] = wl1[2048 + (ks * 8 + w * 2 + nt) * 64 + lane];

    #pragma unroll
    for (int jb = 0; jb < 4; jb++) {
        floatx4 acc2[5][2] = {};
        const short8* fcur = (jb & 1) ? f1 : f0;   // compile-time resolved (unrolled)
        #pragma unroll
        for (int ks = 0; ks < 4; ks++) {
            short8 bf0 = fcur[ks * 2 + 0];
            short8 bf1 = fcur[ks * 2 + 1];
            #pragma unroll
            for (int mt = 0; mt < 5; mt++) {
                short8 a = *(const short8*)&sm.p2.abf[mt * 16 + m][ks * 32 + q * 8];
                acc2[mt][0] = __builtin_amdgcn_mfma_f32_16x16x32_bf16(a, bf0, acc2[mt][0], 0, 0, 0);
                acc2[mt][1] = __builtin_amdgcn_mfma_f32_16x16x32_bf16(a, bf1, acc2[mt][1], 0, 0, 0);
            }
        }
        // prefetch jb+2 into the buffer just consumed
        if (jb < 2) {
            short8* fnext = (jb & 1) ? f1 : f0;
            #pragma unroll
            for (int ks = 0; ks < 4; ks++)
                #pragma unroll
                for (int nt = 0; nt < 2; nt++)
                    fnext[ks * 2 + nt] = wl1[(size_t)(jb + 2) * 2048 + (ks * 8 + w * 2 + nt) * 64 + lane];
        }
        #pragma unroll
        for (int nt = 0; nt < 2; nt++) {
            int j = jb * 128 + w * 32 + nt * 16 + m;
            float blv = bl1[j];
            float vsum = 0.f;
            #pragma unroll
            for (int mt = 0; mt < 5; mt++)
                #pragma unroll
                for (int r = 0; r < 4; r++) {
                    float v = acc2[mt][nt][r] + blv;
                    vsum += v > 0.f ? v : 0.f;
                }
            vsum += __shfl_xor(vsum, 16, 64);
            vsum += __shfl_xor(vsum, 32, 64);
            if (q == 0) atomicAdd(&A_acc[(size_t)b * H1 + j], vsum);
        }
    }
}

// ------- final: out = A_acc @ Wl2 / 512 + bl2 * (400/512), 1 batch/block ---
__global__ __launch_bounds__(256) void final_out(
    const float* __restrict__ A_acc, const float* __restrict__ Wl2,
    const float* __restrict__ bl2, float* __restrict__ out)
{
    __shared__ float a[H1];
    int b = blockIdx.x, tid = threadIdx.x;
    a[tid] = A_acc[(size_t)b * H1 + tid];
    a[tid + 256] = A_acc[(size_t)b * H1 + tid + 256];
    __syncthreads();
    float acc = 0.f;
    #pragma unroll 8
    for (int k = 0; k < H1; k++)
        acc += a[k] * Wl2[(size_t)k * HS + tid];
    out[(size_t)b * HS + tid] = acc * (1.0f / 512.0f) + bl2[tid] * (400.0f / 512.0f);
}

extern "C" void kernel_launch(void* const* d_in, const int* in_sizes, int n_in,
                              void* d_out, int out_size, void* d_ws, size_t ws_size,
                              hipStream_t stream)
{
    const float* emb       = (const float*)d_in[0];
    const int*   x_tokens  = (const int*)d_in[1];
    // d_in[2..6]: edge_src/edge_dst DEAD; batch_ids/pos_ids arithmetic; mask analytic
    const float* emb_table = (const float*)d_in[7];
    // d_in[8..21]: W_e2g/b_e2g + all GAT params: DEAD
    const float* W_le = (const float*)d_in[22];
    const float* b_le = (const float*)d_in[23];
    const float* k7   = (const float*)d_in[24];
    const float* cb7  = (const float*)d_in[25];
    const float* k11  = (const float*)d_in[26];
    const float* cb11 = (const float*)d_in[27];
    const float* k15  = (const float*)d_in[28];
    const float* cb15 = (const float*)d_in[29];
    const float* Wl1  = (const float*)d_in[30];
    const float* bl1  = (const float*)d_in[31];
    const float* Wl2  = (const float*)d_in[32];
    const float* bl2  = (const float*)d_in[33];
    float* out = (float*)d_out;

    char* p = (char*)d_ws;
    unsigned short* seqb = (unsigned short*)p;       p += (size_t)NBATCH * SPAD * HS * 2;
    unsigned short* Wpk = (unsigned short*)p;        p += (size_t)NTAP * HS * OC * 2;
    unsigned short* Wle_pk = (unsigned short*)p;     p += (size_t)KDIM * HS * 2;
    unsigned short* Wl1_pk = (unsigned short*)p;     p += (size_t)OC * H1 * 2;
    float* bcv = (float*)p;                          p += 512;
    float* A_acc = (float*)p;                        p += (size_t)NBATCH * H1 * 4;

    setup_all<<<dim3(3456), 256, 0, stream>>>(
        k7, k11, k15, cb7, cb11, cb15, W_le, Wl1,
        Wpk, bcv, Wle_pk, Wl1_pk, seqb, A_acc);
    gemm_emb<<<dim3(NNODES / 128), 256, 0, stream>>>(
        emb, x_tokens, emb_table, Wle_pk, b_le, seqb);
    conv_fused<<<dim3(5, NBATCH), 256, 0, stream>>>(
        seqb, Wpk, bcv, Wl1_pk, bl1, A_acc);
    final_out<<<NBATCH, 256, 0, stream>>>(A_acc, Wl2, bl2, out);
}

// Round 3
// 577.312 us; speedup vs baseline: 1.1056x; 1.1056x over previous
//
#include <hip/hip_runtime.h>

#define NNODES 102400
#define NBATCH 256
#define LSEQ   400
#define SPAD   416   // 8 zero pad rows each side of the 400 valid positions
#define HS     256
#define KDIM   640
#define OC     128
#define NTAP   15
#define H1     512
#define STILE  80    // 5 * 80 = 400 exact: no M-padding waste, no s-guards
#define SROWS  94    // STILE + 14 halo rows

typedef __attribute__((ext_vector_type(8))) short short8;
typedef __attribute__((ext_vector_type(4))) float floatx4;

__device__ inline unsigned short f2bf(float f) {
    unsigned u = __builtin_bit_cast(unsigned, f);
    unsigned r = (u + 0x7FFFu + ((u >> 16) & 1u)) >> 16;
    return (unsigned short)r;
}

__device__ inline void gld_lds16(const void* g, void* l) {
    __builtin_amdgcn_global_load_lds(
        (const __attribute__((address_space(1))) unsigned int*)g,
        (__attribute__((address_space(3))) unsigned int*)l, 16, 0, 0);
}

// ------- fused setup: seq pad-zero, A_acc zero, conv-kernel combine, packs -
__global__ __launch_bounds__(256) void setup_all(
    const float* __restrict__ k7, const float* __restrict__ k11,
    const float* __restrict__ k15, const float* __restrict__ cb7,
    const float* __restrict__ cb11, const float* __restrict__ cb15,
    const float* __restrict__ W_le, const float* __restrict__ Wl1,
    unsigned short* __restrict__ Wpk, float* __restrict__ bc,
    unsigned short* __restrict__ Wle_pk, unsigned short* __restrict__ Wl1_pk,
    unsigned short* __restrict__ seq, float* __restrict__ A_acc)
{
    int bid = blockIdx.x, tid = threadIdx.x;
    if (bid < 512) {
        // zero only the 16 pad rows per batch (replaces 54 MB memset)
        int idx = bid * 256 + tid;                 // 256 batches * 512 uint4
        int b = idx >> 9, within = idx & 511;
        int rowi = within >> 5, c = within & 31;
        int srow = rowi < 8 ? rowi : 400 + rowi;
        ((uint4*)seq)[((size_t)b * SPAD + srow) * 32 + c] = make_uint4(0u, 0u, 0u, 0u);
    } else if (bid < 2432) {
        // combine k7/k11/k15 (+/3) into one 15-tap weight, MFMA B-frag order
        int idx = (bid - 512) * 256 + tid;         // 15*256*128 = 1920 blocks exact
        int oc = idx & (OC - 1);
        int ic = (idx >> 7) & (HS - 1);
        int d  = idx / (OC * HS);
        float wv = k15[(oc * HS + ic) * 15 + d];
        int t11 = d - 2;
        if (t11 >= 0 && t11 < 11) wv += k11[(oc * HS + ic) * 11 + t11];
        int t7 = d - 4;
        if (t7 >= 0 && t7 < 7)   wv += k7[(oc * HS + ic) * 7 + t7];
        wv *= (1.0f / 3.0f);
        int kc = ic >> 6, ks = (ic >> 5) & 1, qq = (ic >> 3) & 3, j = ic & 7;
        int nt = oc >> 4, n = oc & 15;
        int pidx = ((((d * 4 + kc) * 2 + ks) * 8 + nt) * 64 + (qq * 16 + n)) * 8 + j;
        Wpk[pidx] = f2bf(wv);
        if (idx < OC) bc[idx] = (cb7[idx] + cb11[idx] + cb15[idx]) * (1.0f / 3.0f);
    } else if (bid < 3072) {
        // pack W_le [640][256] -> bf16 fragment order (10 stages of BK=64)
        int idx = (bid - 2432) * 256 + tid;        // 640*256 = 640 blocks
        int k = idx >> 8, col = idx & 255;
        int t = k >> 6, ks = (k >> 5) & 1, qq = (k >> 3) & 3, j = k & 7;
        int nt = col >> 4, n = col & 15;
        int pidx = (((t * 2 + ks) * 16 + nt) * 64 + (qq * 16 + n)) * 8 + j;
        Wle_pk[pidx] = f2bf(W_le[k * 256 + col]);
    } else if (bid < 3328) {
        // pack Wl1 [128][512] -> bf16 fragment order (4 j-blocks of 128)
        int idx = (bid - 3072) * 256 + tid;        // 128*512 = 256 blocks
        int k = idx >> 9, col = idx & 511;
        int ks = k >> 5, qq = (k >> 3) & 3, j = k & 7;
        int jbb = col >> 7, nhnt = (col >> 4) & 7, n = col & 15;
        int pidx = jbb * 16384 + ((ks * 8 + nhnt) * 64 + (qq * 16 + n)) * 8 + j;
        Wl1_pk[pidx] = f2bf(Wl1[k * 512 + col]);
    } else {
        // zero A_acc: 256*512 f32 = 32768 float4 = 128 blocks
        int idx = (bid - 3328) * 256 + tid;
        ((float4*)A_acc)[idx] = make_float4(0.f, 0.f, 0.f, 0.f);
    }
}

// ------- MFMA: relu(emb @ W_le + b_le), + (x_r + .)/2 scatter into bf16 seq
// v3: 64x256 tile, 512 threads / 8 waves. Per-wave tile 32x64 -> acc[2][4]
// = 32 AGPR (round-2's acc[4][8]=128 AGPR + 196 VGPR = 1 wave/SIMD was the
// regression: OccupancyPercent 9.5%). Target: <=128 regs, 4 waves/SIMD,
// 2 blocks/CU = 16 waves/CU for latency hiding on the emb HBM stream.
union GemmSm {
    struct { unsigned short As[64][72]; unsigned short Bsh[16384]; } s;  // 41984 B
    unsigned short Cs[64][264];                                          // 33792 B
};

__global__ __launch_bounds__(512, 4) void gemm_emb(
    const float* __restrict__ emb, const int* __restrict__ x_tokens,
    const float* __restrict__ emb_table,
    const unsigned short* __restrict__ Wle_pk, const float* __restrict__ b_le,
    unsigned short* __restrict__ seq)
{
    __shared__ __align__(16) GemmSm g;
    int row0 = blockIdx.x * 64;
    int tid = threadIdx.x;              // 0..511
    int w = tid >> 6, lane = tid & 63;
    int q = lane >> 4, m = lane & 15;
    int mh = w >> 2, nh = w & 3;        // 2 row-halves x 4 col-quarters

    int ar = tid >> 3;                  // 64 rows, 8 threads per row
    int ac = (tid & 7) * 8;             // 8 floats (2 float4) per thread

    floatx4 acc[2][4] = {};
    const uint4* wp = (const uint4*)Wle_pk;

    for (int t = 0; t < 10; t++) {
        __syncthreads();
        {
            const float4* src = (const float4*)&emb[(size_t)(row0 + ar) * KDIM + t * 64 + ac];
            #pragma unroll
            for (int u = 0; u < 2; u++) {
                float4 f = src[u];
                ushort4 h;
                h.x = f2bf(f.x); h.y = f2bf(f.y); h.z = f2bf(f.z); h.w = f2bf(f.w);
                *(ushort4*)&g.s.As[ar][ac + u * 4] = h;
            }
        }
        #pragma unroll
        for (int i = 0; i < 4; i++) {
            gld_lds16(wp + (size_t)t * 2048 + i * 512 + tid,
                      &g.s.Bsh[(size_t)(i * 512 + w * 64) * 8]);
        }
        __syncthreads();

        #pragma unroll
        for (int ks = 0; ks < 2; ks++) {
            short8 a0 = *(const short8*)&g.s.As[mh * 32 +  0 + m][ks * 32 + q * 8];
            short8 a1 = *(const short8*)&g.s.As[mh * 32 + 16 + m][ks * 32 + q * 8];
            #pragma unroll
            for (int nt = 0; nt < 4; nt++) {
                short8 bf = *(const short8*)&g.s.Bsh[(size_t)((ks * 16 + nh * 4 + nt) * 64 + lane) * 8];
                acc[0][nt] = __builtin_amdgcn_mfma_f32_16x16x32_bf16(a0, bf, acc[0][nt], 0, 0, 0);
                acc[1][nt] = __builtin_amdgcn_mfma_f32_16x16x32_bf16(a1, bf, acc[1][nt], 0, 0, 0);
            }
        }
    }

    // phase 1: finish elementwise, park bf16 result in LDS tile
    __syncthreads();
    #pragma unroll
    for (int nt = 0; nt < 4; nt++) {
        int col = nh * 64 + nt * 16 + m;
        float blv = b_le[col];
        #pragma unroll
        for (int mt = 0; mt < 2; mt++) {
            #pragma unroll
            for (int r = 0; r < 4; r++) {
                int row = mh * 32 + mt * 16 + q * 4 + r;
                int tok = x_tokens[row0 + row];
                float v = acc[mt][nt][r] + blv;
                v = v > 0.f ? v : 0.f;
                g.Cs[row][col] = f2bf(0.5f * (v + emb_table[tok * HS + col]));
            }
        }
    }
    __syncthreads();
    // phase 2: coalesced row stores; wave w owns rows w*8..w*8+7
    #pragma unroll
    for (int rr = 0; rr < 8; rr++) {
        int node = row0 + w * 8 + rr;
        int b = node / LSEQ;
        int p = node - b * LSEQ;
        ushort4 val = *(const ushort4*)&g.Cs[w * 8 + rr][lane * 4];
        *(ushort4*)&seq[((size_t)b * SPAD + (p + 8)) * HS + lane * 4] = val;
    }
}

// ------- conv + mlp1 fused, v2: 3 blocks/CU (LDS 49632), half-chunk B
// pipeline (32 buffer VGPRs), kh-reduction in two 40-row halves, MLP B
// read direct global->regs (no Bsh, no MLP barriers).
union ConvSm {
    unsigned short As[SROWS][264];                 // 49632 B (conv phase)
    struct {
        float red[40 * 132];                       // 21120 B (half reduction)
        unsigned short abf[STILE][136];            // 21760 B (mlp A-tile)
    } p2;                                          // 42880 B
};

__device__ __forceinline__ void conv_load_Bh(
    const short8* __restrict__ wb, int h, int kh, int nh, int lane, short8 bf[4])
{
    int c = h >> 1, ks = h & 1;
    int d = c >> 1, kc = kh * 2 + (c & 1);
    const short8* bp = wb + (size_t)(d * 4 + kc) * 1024 + nh * 256 + ks * 512 + lane;
    #pragma unroll
    for (int nt = 0; nt < 4; nt++)
        bf[nt] = bp[nt * 64];
}

__device__ __forceinline__ void conv_mfma_half(
    const unsigned short (*As)[264], floatx4 acc[5][4],
    const short8 bf[4], int h, int kh, int m, int q)
{
    int c = h >> 1, ks = h & 1;
    int d = c >> 1, kc = kh * 2 + (c & 1);
    #pragma unroll
    for (int mt = 0; mt < 5; mt++) {
        short8 a = *(const short8*)&As[mt * 16 + m + d][kc * 64 + ks * 32 + q * 8];
        #pragma unroll
        for (int nt = 0; nt < 4; nt++)
            acc[mt][nt] = __builtin_amdgcn_mfma_f32_16x16x32_bf16(a, bf[nt], acc[mt][nt], 0, 0, 0);
    }
}

__global__ __launch_bounds__(256, 3) void conv_fused(
    const unsigned short* __restrict__ seq, const unsigned short* __restrict__ Wpk,
    const float* __restrict__ bc, const unsigned short* __restrict__ Wl1_pk,
    const float* __restrict__ bl1, float* __restrict__ A_acc)
{
    __shared__ __align__(16) ConvSm sm;

    int b  = blockIdx.y;
    int s0 = blockIdx.x * STILE;                 // 0,80,160,240,320
    int tid = threadIdx.x;
    int w = tid >> 6, lane = tid & 63;
    int q = lane >> 4, m = lane & 15;
    int nh = w >> 1, kh = w & 1;

    const short8* wb = (const short8*)Wpk;
    short8 bA[4], bB[4];
    conv_load_Bh(wb, 0, kh, nh, lane, bA);       // overlap with A staging

    // stage A once: seq rows s0+1 .. s0+94, all 256 ic (bf16).
    // Max row = 320+1+93 = 414 < SPAD=416 -> always in-bounds.
    {
        const uint4* sp = (const uint4*)(seq + ((size_t)b * SPAD + s0 + 1) * HS);
        #pragma unroll
        for (int pass = 0; pass < 12; pass++) {
            int idx = pass * 256 + tid;
            if (idx < SROWS * 32) {
                int r = idx >> 5, c = idx & 31;
                *(uint4*)&sm.As[r][c * 8] = sp[r * 32 + c];
            }
        }
    }
    __syncthreads();

    floatx4 acc[5][4] = {};   // 80 s x 64 oc partial (this wave's ic-half)

    // 60 half-chunks = 15 taps x 2 kc x 2 ks, pipelined by one half-chunk
    for (int h = 0; h < 60; h += 2) {
        conv_load_Bh(wb, h + 1, kh, nh, lane, bB);
        conv_mfma_half(sm.As, acc, bA, h, kh, m, q);
        if (h + 2 < 60) conv_load_Bh(wb, h + 2, kh, nh, lane, bA);
        conv_mfma_half(sm.As, acc, bB, h + 1, kh, m, q);
    }

    // ---- kh-pair reduce + bias + bf16 in two 40-row halves ----------------
    float bc0 = bc[lane * 2], bc1 = bc[lane * 2 + 1];
    __syncthreads();                       // all As reads done; alias as p2
    #pragma unroll
    for (int hh = 0; hh < 2; hh++) {
        if (kh == 1) {
            #pragma unroll
            for (int mt = 0; mt < 5; mt++)
                #pragma unroll
                for (int nt = 0; nt < 4; nt++)
                    #pragma unroll
                    for (int r = 0; r < 4; r++) {
                        int row = mt * 16 + q * 4 + r;
                        if (row >= hh * 40 && row < hh * 40 + 40)
                            sm.p2.red[(row - hh * 40) * 132 + nh * 64 + nt * 16 + m] = acc[mt][nt][r];
                    }
        }
        __syncthreads();
        if (kh == 0) {
            #pragma unroll
            for (int mt = 0; mt < 5; mt++)
                #pragma unroll
                for (int nt = 0; nt < 4; nt++)
                    #pragma unroll
                    for (int r = 0; r < 4; r++) {
                        int row = mt * 16 + q * 4 + r;
                        if (row >= hh * 40 && row < hh * 40 + 40)
                            sm.p2.red[(row - hh * 40) * 132 + nh * 64 + nt * 16 + m] += acc[mt][nt][r];
                    }
        }
        __syncthreads();
        // convert 40 rows: each wave 10 rows
        #pragma unroll
        for (int rr = 0; rr < 10; rr++) {
            int lrow = w * 10 + rr;
            float2 v = *(const float2*)&sm.p2.red[lrow * 132 + lane * 2];
            unsigned uo = (unsigned)f2bf(v.x + bc0) | ((unsigned)f2bf(v.y + bc1) << 16);
            *(unsigned*)&sm.p2.abf[hh * 40 + lrow][lane * 2] = uo;
        }
        __syncthreads();                   // red free for next half / abf ready
    }

    // ---- fused MLP1: colsum_s relu(abf @ Wl1 + bl1) -> atomicAdd A_acc ----
    // B frags direct global->reg (each wave uses disjoint cols: LDS staging
    // would save zero L2 traffic). 2-deep jb pipeline, no barriers.
    const short8* wl1 = (const short8*)Wl1_pk;
    short8 f0[8], f1[8];
    #pragma unroll
    for (int ks = 0; ks < 4; ks++)
        #pragma unroll
        for (int nt = 0; nt < 2; nt++)
            f0[ks * 2 + nt] = wl1[(ks * 8 + w * 2 + nt) * 64 + lane];
    #pragma unroll
    for (int ks = 0; ks < 4; ks++)
        #pragma unroll
        for (int nt = 0; nt < 2; nt++)
            f1[ks * 2 + nt] = wl1[2048 + (ks * 8 + w * 2 + nt) * 64 + lane];

    #pragma unroll
    for (int jb = 0; jb < 4; jb++) {
        floatx4 acc2[5][2] = {};
        const short8* fcur = (jb & 1) ? f1 : f0;   // compile-time resolved (unrolled)
        #pragma unroll
        for (int ks = 0; ks < 4; ks++) {
            short8 bf0 = fcur[ks * 2 + 0];
            short8 bf1 = fcur[ks * 2 + 1];
            #pragma unroll
            for (int mt = 0; mt < 5; mt++) {
                short8 a = *(const short8*)&sm.p2.abf[mt * 16 + m][ks * 32 + q * 8];
                acc2[mt][0] = __builtin_amdgcn_mfma_f32_16x16x32_bf16(a, bf0, acc2[mt][0], 0, 0, 0);
                acc2[mt][1] = __builtin_amdgcn_mfma_f32_16x16x32_bf16(a, bf1, acc2[mt][1], 0, 0, 0);
            }
        }
        // prefetch jb+2 into the buffer just consumed
        if (jb < 2) {
            short8* fnext = (jb & 1) ? f1 : f0;
            #pragma unroll
            for (int ks = 0; ks < 4; ks++)
                #pragma unroll
                for (int nt = 0; nt < 2; nt++)
                    fnext[ks * 2 + nt] = wl1[(size_t)(jb + 2) * 2048 + (ks * 8 + w * 2 + nt) * 64 + lane];
        }
        #pragma unroll
        for (int nt = 0; nt < 2; nt++) {
            int j = jb * 128 + w * 32 + nt * 16 + m;
            float blv = bl1[j];
            float vsum = 0.f;
            #pragma unroll
            for (int mt = 0; mt < 5; mt++)
                #pragma unroll
                for (int r = 0; r < 4; r++) {
                    float v = acc2[mt][nt][r] + blv;
                    vsum += v > 0.f ? v : 0.f;
                }
            vsum += __shfl_xor(vsum, 16, 64);
            vsum += __shfl_xor(vsum, 32, 64);
            if (q == 0) atomicAdd(&A_acc[(size_t)b * H1 + j], vsum);
        }
    }
}

// ------- final: out = A_acc @ Wl2 / 512 + bl2 * (400/512), 1 batch/block ---
__global__ __launch_bounds__(256) void final_out(
    const float* __restrict__ A_acc, const float* __restrict__ Wl2,
    const float* __restrict__ bl2, float* __restrict__ out)
{
    __shared__ float a[H1];
    int b = blockIdx.x, tid = threadIdx.x;
    a[tid] = A_acc[(size_t)b * H1 + tid];
    a[tid + 256] = A_acc[(size_t)b * H1 + tid + 256];
    __syncthreads();
    float acc = 0.f;
    #pragma unroll 8
    for (int k = 0; k < H1; k++)
        acc += a[k] * Wl2[(size_t)k * HS + tid];
    out[(size_t)b * HS + tid] = acc * (1.0f / 512.0f) + bl2[tid] * (400.0f / 512.0f);
}

extern "C" void kernel_launch(void* const* d_in, const int* in_sizes, int n_in,
                              void* d_out, int out_size, void* d_ws, size_t ws_size,
                              hipStream_t stream)
{
    const float* emb       = (const float*)d_in[0];
    const int*   x_tokens  = (const int*)d_in[1];
    // d_in[2..6]: edge_src/edge_dst DEAD; batch_ids/pos_ids arithmetic; mask analytic
    const float* emb_table = (const float*)d_in[7];
    // d_in[8..21]: W_e2g/b_e2g + all GAT params: DEAD
    const float* W_le = (const float*)d_in[22];
    const float* b_le = (const float*)d_in[23];
    const float* k7   = (const float*)d_in[24];
    const float* cb7  = (const float*)d_in[25];
    const float* k11  = (const float*)d_in[26];
    const float* cb11 = (const float*)d_in[27];
    const float* k15  = (const float*)d_in[28];
    const float* cb15 = (const float*)d_in[29];
    const float* Wl1  = (const float*)d_in[30];
    const float* bl1  = (const float*)d_in[31];
    const float* Wl2  = (const float*)d_in[32];
    const float* bl2  = (const float*)d_in[33];
    float* out = (float*)d_out;

    char* p = (char*)d_ws;
    unsigned short* seqb = (unsigned short*)p;       p += (size_t)NBATCH * SPAD * HS * 2;
    unsigned short* Wpk = (unsigned short*)p;        p += (size_t)NTAP * HS * OC * 2;
    unsigned short* Wle_pk = (unsigned short*)p;     p += (size_t)KDIM * HS * 2;
    unsigned short* Wl1_pk = (unsigned short*)p;     p += (size_t)OC * H1 * 2;
    float* bcv = (float*)p;                          p += 512;
    float* A_acc = (float*)p;                        p += (size_t)NBATCH * H1 * 4;

    setup_all<<<dim3(3456), 256, 0, stream>>>(
        k7, k11, k15, cb7, cb11, cb15, W_le, Wl1,
        Wpk, bcv, Wle_pk, Wl1_pk, seqb, A_acc);
    gemm_emb<<<dim3(NNODES / 64), 512, 0, stream>>>(
        emb, x_tokens, emb_table, Wle_pk, b_le, seqb);
    conv_fused<<<dim3(5, NBATCH), 256, 0, stream>>>(
        seqb, Wpk, bcv, Wl1_pk, bl1, A_acc);
    final_out<<<NBATCH, 256, 0, stream>>>(A_acc, Wl2, bl2, out);
}